// Round 5
// baseline (565.046 us; speedup 1.0000x reference)
//
#include <hip/hip_runtime.h>
#include <math.h>

#define N_NODES 100000
#define N_EDGES 3200000
#define D_IN    256
#define D_HID   32
#define N_CLS   40

#define NPART  196        // partition = dst >> 9 (512 nodes each)
#define HROW   200        // padded histmat row
#define NB1    256
#define CHUNK1 12500      // 256 * 12500 = 3.2M
#define SUB    2500       // 5 sub-chunks per block

typedef unsigned int u32;
typedef unsigned short u16;

__device__ __forceinline__ float bf2f(u16 v) {
    return __uint_as_float(((u32)v) << 16);
}
__device__ __forceinline__ u16 f2bf(float f) {
    u32 u = __float_as_uint(f);
    u32 r = u + 0x7FFFu + ((u >> 16) & 1u);   // round-to-nearest-even
    return (u16)(r >> 16);
}

// ---------------- pass A: per-(block,partition) histogram ----------------

__global__ __launch_bounds__(256) void k_histA(const int* __restrict__ col,
                                               u32* __restrict__ histmat) {
    __shared__ u32 h[256];
    int t = threadIdx.x;
    h[t] = 0;
    __syncthreads();
    int s = blockIdx.x * CHUNK1;
    for (int i = s + t; i < s + CHUNK1; i += 256)
        atomicAdd(&h[((u32)col[i]) >> 9], 1u);
    __syncthreads();
    if (t < HROW) histmat[blockIdx.x * HROW + t] = (t < NPART) ? h[t] : 0u;
}

// ---------------- pass B: column-scan histmat -> per-(block,part) bases; cstart ----------------

__global__ __launch_bounds__(256) void k_scanA(u32* __restrict__ histmat,
                                               int* __restrict__ cstart) {
    __shared__ u32 sc[256];
    int p = threadIdx.x;
    u32 run = 0;
    for (int b = 0; b < NB1; ++b) {
        u32 v = (p < NPART) ? histmat[b * HROW + p] : 0u;
        if (p < NPART) histmat[b * HROW + p] = run;   // excl. within-partition offset
        run += v;
    }
    u32 own = (p < NPART) ? run : 0u;
    sc[p] = own;
    __syncthreads();
    for (int off = 1; off < 256; off <<= 1) {
        u32 v = (p >= off) ? sc[p - off] : 0u;
        __syncthreads();
        sc[p] += v;
        __syncthreads();
    }
    if (p < NPART) cstart[p] = (int)(sc[p] - own);
    if (p == NPART - 1) cstart[NPART] = (int)sc[p];
}

// ---------------- pass C: deterministic partition (LDS local sort, ordered flush) ----------------
// entry: x = (local9 << 17) | src17 ; y = w bits

__global__ __launch_bounds__(256) void k_part(const int* __restrict__ row,
                                              const int* __restrict__ col,
                                              const float* __restrict__ w,
                                              const u32* __restrict__ histmat,
                                              const int* __restrict__ cstart,
                                              uint2* __restrict__ coarse) {
    __shared__ u32 shist[256], sscan[256], scur[256], gbase[256], rcur[256];
    __shared__ uint2 stage[SUB];
    __shared__ u32 gdst[SUB];
    int t = threadIdx.x;
    rcur[t] = (t < NPART) ? ((u32)cstart[t] + histmat[blockIdx.x * HROW + t]) : 0u;
    int s0 = blockIdx.x * CHUNK1;

    for (int sc_ = 0; sc_ < CHUNK1; sc_ += SUB) {
        int s = s0 + sc_;
        shist[t] = 0;
        __syncthreads();
        for (int i = s + t; i < s + SUB; i += 256)
            atomicAdd(&shist[((u32)col[i]) >> 9], 1u);
        __syncthreads();
        u32 own = shist[t];
        sscan[t] = own;
        __syncthreads();
        for (int off = 1; off < 256; off <<= 1) {
            u32 v = (t >= off) ? sscan[t - off] : 0u;
            __syncthreads();
            sscan[t] += v;
            __syncthreads();
        }
        u32 exc = sscan[t] - own;
        scur[t]  = exc;
        gbase[t] = rcur[t] - exc;
        __syncthreads();
        for (int i = s + t; i < s + SUB; i += 256) {
            u32 c = (u32)col[i];
            u32 pid = c >> 9;
            u32 pos = atomicAdd(&scur[pid], 1u);
            stage[pos] = make_uint2(((c & 511u) << 17) | (u32)row[i], __float_as_uint(w[i]));
            gdst[pos]  = gbase[pid] + pos;
        }
        __syncthreads();
        for (int i = t; i < SUB; i += 256) coarse[gdst[i]] = stage[i];
        rcur[t] += shist[t];
        __syncthreads();
    }
}

// ---------------- pass D: per-partition {degree -> dis, node offsets, CSR fill} ----------------
// csr entry: (src17 << 15) | qw15,  qw = round(w * 32768)

__global__ __launch_bounds__(256) void k_part2(const uint2* __restrict__ coarse,
                                               const int* __restrict__ cstart,
                                               float* __restrict__ dis,
                                               int* __restrict__ startp,
                                               u32* __restrict__ csr) {
    __shared__ float wsuml[512];
    __shared__ u32 cntl[512];
    __shared__ u32 curl[512];
    __shared__ u32 psum[256];
    int p = blockIdx.x, t = threadIdx.x;
    int s = cstart[p], e = cstart[p + 1];
    int nbase = p << 9;

    cntl[t] = 0; cntl[t + 256] = 0;
    wsuml[t] = 0.f; wsuml[t + 256] = 0.f;
    __syncthreads();
    for (int i = s + t; i < e; i += 256) {
        uint2 en = coarse[i];
        u32 l = en.x >> 17;
        atomicAdd(&cntl[l], 1u);
        atomicAdd(&wsuml[l], __uint_as_float(en.y));
    }
    __syncthreads();
    for (int l = t; l < 512; l += 256) {
        int node = nbase + l;
        if (node < N_NODES) dis[node] = rsqrtf(1.0f + wsuml[l]);
    }
    // exclusive scan of cntl[0..512) via pair-scan
    u32 a0 = cntl[2 * t], a1 = cntl[2 * t + 1];
    psum[t] = a0 + a1;
    __syncthreads();
    for (int off = 1; off < 256; off <<= 1) {
        u32 v = (t >= off) ? psum[t - off] : 0u;
        __syncthreads();
        psum[t] += v;
        __syncthreads();
    }
    u32 excl = psum[t] - (a0 + a1);
    u32 c0 = (u32)s + excl, c1 = c0 + a0;
    curl[2 * t] = c0; curl[2 * t + 1] = c1;
    int n0 = nbase + 2 * t, n1 = n0 + 1;
    if (n0 < N_NODES) startp[n0] = (int)c0;
    if (n1 < N_NODES) startp[n1] = (int)c1;
    if (p == NPART - 1 && t == 255) startp[N_NODES] = e;
    __syncthreads();
    for (int i = s + t; i < e; i += 256) {
        uint2 en = coarse[i];
        u32 l = en.x >> 17;
        u32 src = en.x & 0x1FFFFu;
        float wv = __uint_as_float(en.y);
        u32 q = (u32)(wv * 32768.0f + 0.5f);
        if (q > 32767u) q = 32767u;
        u32 pos = atomicAdd(&curl[l], 1u);
        csr[pos] = (src << 15) | q;
    }
}

// ---------------- GEMM1: g0 = dis .* (x @ Wc^T), bf16 out ----------------

#define LSTRIDE 260

__global__ __launch_bounds__(256) void k_gemm1(const float* __restrict__ x,
                                               const float* __restrict__ Wc,
                                               const float* __restrict__ dis,
                                               u16* __restrict__ g) {
    __shared__ float xs[32 * LSTRIDE];
    __shared__ float wsl[32 * LSTRIDE];
    const int tid  = threadIdx.x;
    const int base = blockIdx.x * 32;

    for (int i = tid; i < 2048; i += 256) {
        int r = i >> 6, j = i & 63;
        float4 v = reinterpret_cast<const float4*>(x)[(size_t)(base + r) * 64 + j];
        *reinterpret_cast<float4*>(&xs[r * LSTRIDE + j * 4]) = v;
    }
    for (int i = tid; i < 2048; i += 256) {
        int r = i >> 6, j = i & 63;
        float4 v = reinterpret_cast<const float4*>(Wc)[i];
        *reinterpret_cast<float4*>(&wsl[r * LSTRIDE + j * 4]) = v;
    }
    __syncthreads();

    const int node = tid >> 3;
    const int og   = tid & 7;
    float4 acc = make_float4(0.f, 0.f, 0.f, 0.f);
    const float* xrow = &xs[node * LSTRIDE];
    const float* w0 = &wsl[(og     ) * LSTRIDE];
    const float* w1 = &wsl[(og +  8) * LSTRIDE];
    const float* w2 = &wsl[(og + 16) * LSTRIDE];
    const float* w3 = &wsl[(og + 24) * LSTRIDE];

#pragma unroll 4
    for (int k = 0; k < 256; k += 4) {
        float4 xv = *reinterpret_cast<const float4*>(&xrow[k]);
        float4 a4 = *reinterpret_cast<const float4*>(&w0[k]);
        float4 b4 = *reinterpret_cast<const float4*>(&w1[k]);
        float4 c4 = *reinterpret_cast<const float4*>(&w2[k]);
        float4 d4 = *reinterpret_cast<const float4*>(&w3[k]);
        acc.x += xv.x * a4.x + xv.y * a4.y + xv.z * a4.z + xv.w * a4.w;
        acc.y += xv.x * b4.x + xv.y * b4.y + xv.z * b4.z + xv.w * b4.w;
        acc.z += xv.x * c4.x + xv.y * c4.y + xv.z * c4.z + xv.w * c4.w;
        acc.w += xv.x * d4.x + xv.y * d4.y + xv.z * d4.z + xv.w * d4.w;
    }
    float dv = dis[base + node];
    size_t gb = (size_t)(base + node) * D_HID;
    g[gb + og     ] = f2bf(acc.x * dv);
    g[gb + og +  8] = f2bf(acc.y * dv);
    g[gb + og + 16] = f2bf(acc.z * dv);
    g[gb + og + 24] = f2bf(acc.w * dv);
}

// ---------------- pull hop in g-space ----------------
// out[c] = sc * (g[c] + sum_e w_e * g[src]),  sc = dis^2 (hops 1,2) or dis (hop 3)

__global__ __launch_bounds__(256) void k_pull(const int* __restrict__ start,
                                              const u32* __restrict__ csr,
                                              const float* __restrict__ dis,
                                              const u16* __restrict__ h,
                                              u16* __restrict__ out,
                                              int sq) {
    int g    = blockIdx.x * 8 + (threadIdx.x >> 5);
    int lane = threadIdx.x & 31;
    if (g >= N_NODES) return;

    int s = start[g];
    int e = start[g + 1];
    float acc = bf2f(h[(size_t)g * D_HID + lane]);

    for (int base = s; base < e; base += 32) {
        int idx = base + lane;
        u32 p = (idx < e) ? csr[idx] : 0u;   // pad: src=0, w=0
        int rem = e - base;
        for (int jj = 0; jj < 32; jj += 8) {
            if (jj >= rem) break;
#pragma unroll
            for (int j = 0; j < 8; ++j) {
                u32 pj = __shfl(p, jj + j, 32);
                float nv = (float)(pj & 32767u) * (1.0f / 32768.0f);
                u32 src = pj >> 15;
                acc += nv * bf2f(h[(size_t)src * D_HID + lane]);
            }
        }
    }
    float sc = dis[g];
    if (sq) sc *= sc;
    out[(size_t)g * D_HID + lane] = f2bf(sc * acc);
}

// ---------------- epilogue: bias + ELU + FC + log_softmax ----------------

__global__ __launch_bounds__(256) void k_final(const u16* __restrict__ h,
                                               const float* __restrict__ bc,
                                               const float* __restrict__ Wfc,
                                               const float* __restrict__ bf,
                                               float* __restrict__ out) {
    __shared__ float wf[N_CLS * D_HID];
    __shared__ float bcs[D_HID];
    __shared__ float bfs[N_CLS];
    const int tid = threadIdx.x;
    for (int i = tid; i < N_CLS * D_HID; i += 256) wf[i] = Wfc[i];
    if (tid < D_HID) bcs[tid] = bc[tid];
    if (tid < N_CLS) bfs[tid] = bf[tid];
    __syncthreads();

    int node = blockIdx.x * 256 + tid;
    if (node >= N_NODES) return;

    float a[D_HID];
    const u32* hp = reinterpret_cast<const u32*>(h + (size_t)node * D_HID);
#pragma unroll
    for (int j = 0; j < 16; ++j) {
        u32 v = hp[j];
        float z0 = bf2f((u16)(v & 0xFFFFu)) + bcs[j * 2 + 0];
        float z1 = bf2f((u16)(v >> 16))     + bcs[j * 2 + 1];
        a[j * 2 + 0] = z0 > 0.f ? z0 : expm1f(z0);
        a[j * 2 + 1] = z1 > 0.f ? z1 : expm1f(z1);
    }

    float logits[N_CLS];
    float m = -1e30f;
#pragma unroll
    for (int c = 0; c < N_CLS; ++c) {
        float accv = bfs[c];
        const float* wr = &wf[c * D_HID];
#pragma unroll
        for (int o = 0; o < D_HID; ++o) accv += a[o] * wr[o];
        logits[c] = accv;
        m = fmaxf(m, accv);
    }
    float sum = 0.f;
#pragma unroll
    for (int c = 0; c < N_CLS; ++c) sum += expf(logits[c] - m);
    float lse = m + logf(sum);
    float* op = out + (size_t)node * N_CLS;
#pragma unroll
    for (int c = 0; c < N_CLS; ++c) op[c] = logits[c] - lse;
}

// ---------------- launch ----------------

extern "C" void kernel_launch(void* const* d_in, const int* in_sizes, int n_in,
                              void* d_out, int out_size, void* d_ws, size_t ws_size,
                              hipStream_t stream) {
    const float* x   = (const float*)d_in[0];
    const int*   ei  = (const int*)d_in[1];
    const float* ea  = (const float*)d_in[2];
    const float* Wc  = (const float*)d_in[3];
    const float* bc  = (const float*)d_in[4];
    const float* Wfc = (const float*)d_in[5];
    const float* bf  = (const float*)d_in[6];
    float* out = (float*)d_out;
    float* ws  = (float*)d_ws;

    const int* row = ei;             // edge_index[0]
    const int* col = ei + N_EDGES;   // edge_index[1]

    // workspace layout (float-element offsets; base 256B aligned)
    float* dis     = ws;                         // 100000
    int*   cstart  = (int*)(ws + 100000);        // 197 -> pad to 100224
    u32*   histmat = (u32*)(ws + 100224);        // 256*200 = 51200 -> 151424
    int*   startp  = (int*)(ws + 151424);        // 100001 -> pad 251428 (even)
    uint2* coarse  = (uint2*)(ws + 251428);      // 3.2M uint2 = 6.4M floats -> 6651428
    u32*   csr     = (u32*)(ws + 6651428);       // 3.2M u32 -> 9851428
    // bufA/bufB alias coarse's region (coarse is dead after k_part2)
    u16*   bufA    = (u16*)(ws + 251428);        // 3.2M u16 = 1.6M floats
    u16*   bufB    = (u16*)(ws + 1851428);       // 3.2M u16
    // total 9,851,428 floats = 39.4 MB

    const int GN = (N_NODES + 255) / 256;    // 391
    const int GP = (N_NODES + 7) / 8;        // 12500

    k_histA <<<NB1, 256, 0, stream>>>(col, histmat);
    k_scanA <<<1, 256, 0, stream>>>(histmat, cstart);
    k_part  <<<NB1, 256, 0, stream>>>(row, col, ea, histmat, cstart, coarse);
    k_part2 <<<NPART, 256, 0, stream>>>(coarse, cstart, dis, startp, csr);

    k_gemm1 <<<N_NODES / 32, 256, 0, stream>>>(x, Wc, dis, bufA);

    k_pull  <<<GP, 256, 0, stream>>>(startp, csr, dis, bufA, bufB, 1);
    k_pull  <<<GP, 256, 0, stream>>>(startp, csr, dis, bufB, bufA, 1);
    k_pull  <<<GP, 256, 0, stream>>>(startp, csr, dis, bufA, bufB, 0);

    k_final <<<GN, 256, 0, stream>>>(bufB, bc, Wfc, bf, out);
}

// Round 6
// 561.738 us; speedup vs baseline: 1.0059x; 1.0059x over previous
//
#include <hip/hip_runtime.h>
#include <math.h>

#define N_NODES 100000
#define N_EDGES 3200000
#define D_IN    256
#define D_HID   32
#define N_CLS   40

#define NPART  196        // partition = dst >> 9 (512 nodes each)
#define HROW   200        // padded histmat row
#define NB1    256
#define CHUNK1 12500      // 256 * 12500 = 3.2M
#define SUB    2500       // 5 sub-chunks per block

typedef unsigned int u32;
typedef unsigned short u16;

__device__ __forceinline__ float bf2f(u16 v) {
    return __uint_as_float(((u32)v) << 16);
}
__device__ __forceinline__ u16 f2bf(float f) {
    u32 u = __float_as_uint(f);
    u32 r = u + 0x7FFFu + ((u >> 16) & 1u);   // round-to-nearest-even
    return (u16)(r >> 16);
}
__device__ __forceinline__ u32 pack2bf(float lo, float hi) {
    return (u32)f2bf(lo) | ((u32)f2bf(hi) << 16);
}

#if defined(__has_builtin)
#if __has_builtin(__builtin_amdgcn_fdot2_f32_bf16)
#define HAVE_DOT2 1
#endif
#endif

#ifdef HAVE_DOT2
typedef __bf16 bf16x2 __attribute__((ext_vector_type(2)));
#endif

__device__ __forceinline__ float dot2bf(u32 a, u32 b, float c) {
#ifdef HAVE_DOT2
    return __builtin_amdgcn_fdot2_f32_bf16(__builtin_bit_cast(bf16x2, a),
                                           __builtin_bit_cast(bf16x2, b), c, false);
#else
    float al = __uint_as_float(a << 16), ah = __uint_as_float(a & 0xFFFF0000u);
    float bl = __uint_as_float(b << 16), bh = __uint_as_float(b & 0xFFFF0000u);
    return c + al * bl + ah * bh;
#endif
}

// ---------------- pass A: per-(block,partition) histogram ----------------

__global__ __launch_bounds__(256) void k_histA(const int* __restrict__ col,
                                               u32* __restrict__ histmat) {
    __shared__ u32 h[256];
    int t = threadIdx.x;
    h[t] = 0;
    __syncthreads();
    int s = blockIdx.x * CHUNK1;
    for (int i = s + t; i < s + CHUNK1; i += 256)
        atomicAdd(&h[((u32)col[i]) >> 9], 1u);
    __syncthreads();
    if (t < HROW) histmat[blockIdx.x * HROW + t] = (t < NPART) ? h[t] : 0u;
}

// ---------------- pass B: column-scan histmat -> per-(block,part) bases; cstart ----------------

__global__ __launch_bounds__(256) void k_scanA(u32* __restrict__ histmat,
                                               int* __restrict__ cstart) {
    __shared__ u32 sc[256];
    int p = threadIdx.x;
    u32 run = 0;
    for (int b = 0; b < NB1; ++b) {
        u32 v = (p < NPART) ? histmat[b * HROW + p] : 0u;
        if (p < NPART) histmat[b * HROW + p] = run;   // excl. within-partition offset
        run += v;
    }
    u32 own = (p < NPART) ? run : 0u;
    sc[p] = own;
    __syncthreads();
    for (int off = 1; off < 256; off <<= 1) {
        u32 v = (p >= off) ? sc[p - off] : 0u;
        __syncthreads();
        sc[p] += v;
        __syncthreads();
    }
    if (p < NPART) cstart[p] = (int)(sc[p] - own);
    if (p == NPART - 1) cstart[NPART] = (int)sc[p];
}

// ---------------- pass C: deterministic partition (LDS local sort, ordered flush) ----------------
// entry: x = (local9 << 17) | src17 ; y = w bits

__global__ __launch_bounds__(256) void k_part(const int* __restrict__ row,
                                              const int* __restrict__ col,
                                              const float* __restrict__ w,
                                              const u32* __restrict__ histmat,
                                              const int* __restrict__ cstart,
                                              uint2* __restrict__ coarse) {
    __shared__ u32 shist[256], sscan[256], scur[256], gbase[256], rcur[256];
    __shared__ uint2 stage[SUB];
    __shared__ u32 gdst[SUB];
    int t = threadIdx.x;
    rcur[t] = (t < NPART) ? ((u32)cstart[t] + histmat[blockIdx.x * HROW + t]) : 0u;
    int s0 = blockIdx.x * CHUNK1;

    for (int sc_ = 0; sc_ < CHUNK1; sc_ += SUB) {
        int s = s0 + sc_;
        shist[t] = 0;
        __syncthreads();
        for (int i = s + t; i < s + SUB; i += 256)
            atomicAdd(&shist[((u32)col[i]) >> 9], 1u);
        __syncthreads();
        u32 own = shist[t];
        sscan[t] = own;
        __syncthreads();
        for (int off = 1; off < 256; off <<= 1) {
            u32 v = (t >= off) ? sscan[t - off] : 0u;
            __syncthreads();
            sscan[t] += v;
            __syncthreads();
        }
        u32 exc = sscan[t] - own;
        scur[t]  = exc;
        gbase[t] = rcur[t] - exc;
        __syncthreads();
        for (int i = s + t; i < s + SUB; i += 256) {
            u32 c = (u32)col[i];
            u32 pid = c >> 9;
            u32 pos = atomicAdd(&scur[pid], 1u);
            stage[pos] = make_uint2(((c & 511u) << 17) | (u32)row[i], __float_as_uint(w[i]));
            gdst[pos]  = gbase[pid] + pos;
        }
        __syncthreads();
        for (int i = t; i < SUB; i += 256) coarse[gdst[i]] = stage[i];
        rcur[t] += shist[t];
        __syncthreads();
    }
}

// ---------------- pass D: per-partition {degree -> dis, node offsets, CSR fill} ----------------
// csr entry: (src17 << 15) | qw15,  qw = round(w * 32768)

__global__ __launch_bounds__(256) void k_part2(const uint2* __restrict__ coarse,
                                               const int* __restrict__ cstart,
                                               float* __restrict__ dis,
                                               int* __restrict__ startp,
                                               u32* __restrict__ csr) {
    __shared__ float wsuml[512];
    __shared__ u32 cntl[512];
    __shared__ u32 curl[512];
    __shared__ u32 psum[256];
    int p = blockIdx.x, t = threadIdx.x;
    int s = cstart[p], e = cstart[p + 1];
    int nbase = p << 9;

    cntl[t] = 0; cntl[t + 256] = 0;
    wsuml[t] = 0.f; wsuml[t + 256] = 0.f;
    __syncthreads();
    for (int i = s + t; i < e; i += 256) {
        uint2 en = coarse[i];
        u32 l = en.x >> 17;
        atomicAdd(&cntl[l], 1u);
        atomicAdd(&wsuml[l], __uint_as_float(en.y));
    }
    __syncthreads();
    for (int l = t; l < 512; l += 256) {
        int node = nbase + l;
        if (node < N_NODES) dis[node] = rsqrtf(1.0f + wsuml[l]);
    }
    // exclusive scan of cntl[0..512) via pair-scan
    u32 a0 = cntl[2 * t], a1 = cntl[2 * t + 1];
    psum[t] = a0 + a1;
    __syncthreads();
    for (int off = 1; off < 256; off <<= 1) {
        u32 v = (t >= off) ? psum[t - off] : 0u;
        __syncthreads();
        psum[t] += v;
        __syncthreads();
    }
    u32 excl = psum[t] - (a0 + a1);
    u32 c0 = (u32)s + excl, c1 = c0 + a0;
    curl[2 * t] = c0; curl[2 * t + 1] = c1;
    int n0 = nbase + 2 * t, n1 = n0 + 1;
    if (n0 < N_NODES) startp[n0] = (int)c0;
    if (n1 < N_NODES) startp[n1] = (int)c1;
    if (p == NPART - 1 && t == 255) startp[N_NODES] = e;
    __syncthreads();
    for (int i = s + t; i < e; i += 256) {
        uint2 en = coarse[i];
        u32 l = en.x >> 17;
        u32 src = en.x & 0x1FFFFu;
        float wv = __uint_as_float(en.y);
        u32 q = (u32)(wv * 32768.0f + 0.5f);
        if (q > 32767u) q = 32767u;
        u32 pos = atomicAdd(&curl[l], 1u);
        csr[pos] = (src << 15) | q;
    }
}

// ---------------- GEMM1: g0 = dis .* (x @ Wc^T), bf16 LDS + dot2, bf16 out ----------------
// 64 nodes/block; thread: 2 nodes x 4 outs. LDS as packed bf16x2, row stride 130 u32.

#define XST 130

__global__ __launch_bounds__(256) void k_gemm1(const float* __restrict__ x,
                                               const float* __restrict__ Wc,
                                               const float* __restrict__ dis,
                                               u16* __restrict__ g) {
    __shared__ u32 xs[64 * XST];
    __shared__ u32 wsl[32 * XST];
    const int tid  = threadIdx.x;
    const int base = blockIdx.x * 64;
    const int nrows = (N_NODES - base) < 64 ? (N_NODES - base) : 64;

    // stage W: 32 rows x 128 u32 (bf16x2), coalesced float2 loads
    for (int i = tid; i < 4096; i += 256) {
        int r = i >> 7, kk = i & 127;
        float2 v = reinterpret_cast<const float2*>(Wc)[i];
        wsl[r * XST + kk] = pack2bf(v.x, v.y);
    }
    // stage x tile: nrows x 128 u32
    for (int i = tid; i < nrows * 128; i += 256) {
        int r = i >> 7, kk = i & 127;
        float2 v = reinterpret_cast<const float2*>(x)[(size_t)(base + r) * 128 + kk];
        xs[r * XST + kk] = pack2bf(v.x, v.y);
    }
    __syncthreads();

    const int np = tid >> 3;     // 0..31 -> nodes {2np, 2np+1}
    const int og = tid & 7;      // outs {og, og+8, og+16, og+24}
    if (2 * np >= nrows) return;

    const u32* x0 = &xs[(2 * np    ) * XST];
    const u32* x1 = &xs[(2 * np + 1) * XST];
    const u32* w0 = &wsl[(og     ) * XST];
    const u32* w1 = &wsl[(og +  8) * XST];
    const u32* w2 = &wsl[(og + 16) * XST];
    const u32* w3 = &wsl[(og + 24) * XST];

    float a00 = 0.f, a01 = 0.f, a02 = 0.f, a03 = 0.f;
    float a10 = 0.f, a11 = 0.f, a12 = 0.f, a13 = 0.f;

#pragma unroll 4
    for (int kk = 0; kk < 128; kk += 2) {
        uint2 X0 = *reinterpret_cast<const uint2*>(&x0[kk]);
        uint2 X1 = *reinterpret_cast<const uint2*>(&x1[kk]);
        uint2 W0 = *reinterpret_cast<const uint2*>(&w0[kk]);
        uint2 W1 = *reinterpret_cast<const uint2*>(&w1[kk]);
        uint2 W2 = *reinterpret_cast<const uint2*>(&w2[kk]);
        uint2 W3 = *reinterpret_cast<const uint2*>(&w3[kk]);
        a00 = dot2bf(X0.x, W0.x, a00); a00 = dot2bf(X0.y, W0.y, a00);
        a01 = dot2bf(X0.x, W1.x, a01); a01 = dot2bf(X0.y, W1.y, a01);
        a02 = dot2bf(X0.x, W2.x, a02); a02 = dot2bf(X0.y, W2.y, a02);
        a03 = dot2bf(X0.x, W3.x, a03); a03 = dot2bf(X0.y, W3.y, a03);
        a10 = dot2bf(X1.x, W0.x, a10); a10 = dot2bf(X1.y, W0.y, a10);
        a11 = dot2bf(X1.x, W1.x, a11); a11 = dot2bf(X1.y, W1.y, a11);
        a12 = dot2bf(X1.x, W2.x, a12); a12 = dot2bf(X1.y, W2.y, a12);
        a13 = dot2bf(X1.x, W3.x, a13); a13 = dot2bf(X1.y, W3.y, a13);
    }

    int n0 = base + 2 * np;
    float d0 = dis[n0];
    size_t gb0 = (size_t)n0 * D_HID;
    g[gb0 + og     ] = f2bf(a00 * d0);
    g[gb0 + og +  8] = f2bf(a01 * d0);
    g[gb0 + og + 16] = f2bf(a02 * d0);
    g[gb0 + og + 24] = f2bf(a03 * d0);
    if (2 * np + 1 < nrows) {
        float d1 = dis[n0 + 1];
        size_t gb1 = gb0 + D_HID;
        g[gb1 + og     ] = f2bf(a10 * d1);
        g[gb1 + og +  8] = f2bf(a11 * d1);
        g[gb1 + og + 16] = f2bf(a12 * d1);
        g[gb1 + og + 24] = f2bf(a13 * d1);
    }
}

// ---------------- pull hop in g-space: one node per 64-lane wave ----------------
// out[c] = sc * (g[c] + sum_e w_e * g[src]),  sc = dis^2 (hops 1,2) or dis (hop 3)
// lanes 0-31 process even edges, 32-63 odd edges; halves reduced via shfl_xor(32).

__global__ __launch_bounds__(256) void k_pull(const int* __restrict__ start,
                                              const u32* __restrict__ csr,
                                              const float* __restrict__ dis,
                                              const u16* __restrict__ h,
                                              u16* __restrict__ out,
                                              int sq) {
    int wid  = blockIdx.x * 4 + (threadIdx.x >> 6);   // node = wave
    int lane = threadIdx.x & 63;
    int dim  = lane & 31;
    if (wid >= N_NODES) return;

    int s = start[wid];
    int e = start[wid + 1];
    float acc = 0.f;

    for (int base = s; base < e; base += 64) {
        int idx = base + 2 * dim + (lane >> 5);
        u32 p = (idx < e) ? csr[idx] : 0u;            // pad: src=0, w=0
        int rem = e - base;
        int npairs = (rem + 1) >> 1;
        if (npairs > 32) npairs = 32;
        for (int j0 = 0; j0 < 32; j0 += 8) {
            if (j0 >= npairs) break;
#pragma unroll
            for (int j = 0; j < 8; ++j) {
                u32 pj = __shfl(p, j0 + j + (lane & 32), 64);
                float nv = (float)(pj & 32767u) * (1.0f / 32768.0f);
                u32 src = pj >> 15;
                acc += nv * bf2f(h[(size_t)src * D_HID + dim]);
            }
        }
    }
    float tot = acc + __shfl_xor(acc, 32, 64);        // combine halves
    if (lane < 32) {
        tot += bf2f(h[(size_t)wid * D_HID + dim]);    // self term
        float sc = dis[wid];
        if (sq) sc *= sc;
        out[(size_t)wid * D_HID + dim] = f2bf(sc * tot);
    }
}

// ---------------- epilogue: bias + ELU + FC + log_softmax ----------------

__global__ __launch_bounds__(256) void k_final(const u16* __restrict__ h,
                                               const float* __restrict__ bc,
                                               const float* __restrict__ Wfc,
                                               const float* __restrict__ bf,
                                               float* __restrict__ out) {
    __shared__ float wf[N_CLS * D_HID];
    __shared__ float bcs[D_HID];
    __shared__ float bfs[N_CLS];
    const int tid = threadIdx.x;
    for (int i = tid; i < N_CLS * D_HID; i += 256) wf[i] = Wfc[i];
    if (tid < D_HID) bcs[tid] = bc[tid];
    if (tid < N_CLS) bfs[tid] = bf[tid];
    __syncthreads();

    int node = blockIdx.x * 256 + tid;
    if (node >= N_NODES) return;

    float a[D_HID];
    const u32* hp = reinterpret_cast<const u32*>(h + (size_t)node * D_HID);
#pragma unroll
    for (int j = 0; j < 16; ++j) {
        u32 v = hp[j];
        float z0 = bf2f((u16)(v & 0xFFFFu)) + bcs[j * 2 + 0];
        float z1 = bf2f((u16)(v >> 16))     + bcs[j * 2 + 1];
        a[j * 2 + 0] = z0 > 0.f ? z0 : expm1f(z0);
        a[j * 2 + 1] = z1 > 0.f ? z1 : expm1f(z1);
    }

    float logits[N_CLS];
    float m = -1e30f;
#pragma unroll
    for (int c = 0; c < N_CLS; ++c) {
        float accv = bfs[c];
        const float* wr = &wf[c * D_HID];
#pragma unroll
        for (int o = 0; o < D_HID; ++o) accv += a[o] * wr[o];
        logits[c] = accv;
        m = fmaxf(m, accv);
    }
    float sum = 0.f;
#pragma unroll
    for (int c = 0; c < N_CLS; ++c) sum += expf(logits[c] - m);
    float lse = m + logf(sum);
    float* op = out + (size_t)node * N_CLS;
#pragma unroll
    for (int c = 0; c < N_CLS; ++c) op[c] = logits[c] - lse;
}

// ---------------- launch ----------------

extern "C" void kernel_launch(void* const* d_in, const int* in_sizes, int n_in,
                              void* d_out, int out_size, void* d_ws, size_t ws_size,
                              hipStream_t stream) {
    const float* x   = (const float*)d_in[0];
    const int*   ei  = (const int*)d_in[1];
    const float* ea  = (const float*)d_in[2];
    const float* Wc  = (const float*)d_in[3];
    const float* bc  = (const float*)d_in[4];
    const float* Wfc = (const float*)d_in[5];
    const float* bf  = (const float*)d_in[6];
    float* out = (float*)d_out;
    float* ws  = (float*)d_ws;

    const int* row = ei;             // edge_index[0]
    const int* col = ei + N_EDGES;   // edge_index[1]

    // workspace layout (float-element offsets; base 256B aligned)
    float* dis     = ws;                         // 100000
    int*   cstart  = (int*)(ws + 100000);        // 197 -> pad to 100224
    u32*   histmat = (u32*)(ws + 100224);        // 256*200 = 51200 -> 151424
    int*   startp  = (int*)(ws + 151424);        // 100001 -> pad 251428 (even)
    uint2* coarse  = (uint2*)(ws + 251428);      // 3.2M uint2 = 6.4M floats -> 6651428
    u32*   csr     = (u32*)(ws + 6651428);       // 3.2M u32 -> 9851428
    // bufA/bufB alias coarse's region (coarse is dead after k_part2)
    u16*   bufA    = (u16*)(ws + 251428);        // 3.2M u16 = 1.6M floats
    u16*   bufB    = (u16*)(ws + 1851428);       // 3.2M u16
    // total 9,851,428 floats = 39.4 MB

    const int GN = (N_NODES + 255) / 256;    // 391
    const int GG = (N_NODES + 63) / 64;      // 1563
    const int GP = (N_NODES + 3) / 4;        // 25000 (1 node per wave, 4 waves/block)

    k_histA <<<NB1, 256, 0, stream>>>(col, histmat);
    k_scanA <<<1, 256, 0, stream>>>(histmat, cstart);
    k_part  <<<NB1, 256, 0, stream>>>(row, col, ea, histmat, cstart, coarse);
    k_part2 <<<NPART, 256, 0, stream>>>(coarse, cstart, dis, startp, csr);

    k_gemm1 <<<GG, 256, 0, stream>>>(x, Wc, dis, bufA);

    k_pull  <<<GP, 256, 0, stream>>>(startp, csr, dis, bufA, bufB, 1);
    k_pull  <<<GP, 256, 0, stream>>>(startp, csr, dis, bufB, bufA, 1);
    k_pull  <<<GP, 256, 0, stream>>>(startp, csr, dis, bufA, bufB, 0);

    k_final <<<GN, 256, 0, stream>>>(bufB, bc, Wfc, bf, out);
}